// Round 3
// baseline (448.404 us; speedup 1.0000x reference)
//
#include <hip/hip_runtime.h>
#include <stdint.h>

// Problem constants
#define NB   64          // batches
#define NS   64          // sensors
#define NT   2030        // time samples
#define NP   16384       // ROI*ROI pixels
#define DAS_ELEMS (NB * NP)          // 1,048,576

// native clang vector type (usable with __builtin_nontemporal_store)
typedef float v4f __attribute__((ext_vector_type(4)));

// ---------------------------------------------------------------------------
// Kernel 0: transpose geometry (pixel,s) -> (s,pixel), fusing clamp + valid.
// ---------------------------------------------------------------------------
__global__ __launch_bounds__(256) void prep_kernel(
    const int* __restrict__ t_idx, const float* __restrict__ w,
    int* __restrict__ tc, float* __restrict__ wv)
{
    __shared__ int   ti[64][65];
    __shared__ float wf[64][65];
    const int pbase = blockIdx.x * 64;

    #pragma unroll
    for (int k = 0; k < 16; ++k) {
        int o = k * 256 + threadIdx.x;     // 0..4095
        int r = o >> 6, s = o & 63;        // r = pixel-in-tile, s = sensor
        ti[r][s] = t_idx[pbase * 64 + o];
        wf[r][s] = w[pbase * 64 + o];
    }
    __syncthreads();

    #pragma unroll
    for (int k = 0; k < 16; ++k) {
        int o = k * 256 + threadIdx.x;
        int s = o >> 6, r = o & 63;
        int t = ti[r][s];
        bool valid = (t >= 0) & (t < NT);
        int tcl = min(max(t, 0), NT - 1);
        tc[s * NP + pbase + r] = tcl;
        wv[s * NP + pbase + r] = valid ? wf[r][s] : 0.0f;
    }
}

// ---------------------------------------------------------------------------
// Cooperative copy of one sinogram row (2030 floats, 8B-aligned) into LDS.
// 1015 float2 slots over 256 threads.
// ---------------------------------------------------------------------------
static __device__ __forceinline__ void stage_row(
    float* __restrict__ dst, const float* __restrict__ src, int tid)
{
    const float2* __restrict__ s2 = (const float2*)src;
    float2* __restrict__ d2 = (float2*)dst;
    #pragma unroll
    for (int k = 0; k < 4; ++k) {
        int idx = tid + k * 256;
        if (idx < 1015) d2[idx] = s2[idx];
    }
}

// ---------------------------------------------------------------------------
// Kernel 1: main DAS, LDS-staged sinogram rows.
// grid (8 pixel-tiles, 64 batches) x 256 threads; 8 px/thread (2 float4 groups
// 1024 apart); loop over 64 sensors with double-buffered row in LDS.
// ---------------------------------------------------------------------------
__global__ __launch_bounds__(256) void main2_kernel(
    const float* __restrict__ sino,   // (B, S, T)
    const int*   __restrict__ tc,     // (S, NP) clamped
    const float* __restrict__ wv,     // (S, NP) valid-masked
    float*       __restrict__ das,    // (B, NP) raw relu'd sums
    float*       __restrict__ pix,    // (B, S, NP)
    unsigned*    __restrict__ bmax)   // per-batch max (float bits)
{
    __shared__ __align__(16) float row[2][2048];
    const int b   = blockIdx.y;
    const int tid = threadIdx.x;
    const int p   = blockIdx.x * 2048 + tid * 4;
    const float* __restrict__ srow = sino + (size_t)b * (NS * NT);
    float* __restrict__ pixb = pix + (size_t)b * ((size_t)NS * NP);

    stage_row(row[0], srow, tid);

    v4f acc0 = (v4f)(0.0f), acc1 = (v4f)(0.0f);

    for (int s = 0; s < NS; ++s) {
        __syncthreads();                              // row[s&1] ready
        if (s + 1 < NS) stage_row(row[(s + 1) & 1], srow + (s + 1) * NT, tid);

        const float* __restrict__ r = row[s & 1];
        const int4   ta = *(const int4*)  (tc + s * NP + p);
        const float4 wa = *(const float4*)(wv + s * NP + p);
        const int4   tb = *(const int4*)  (tc + s * NP + p + 1024);
        const float4 wb = *(const float4*)(wv + s * NP + p + 1024);

        v4f va, vb;
        va.x = r[ta.x] * wa.x; va.y = r[ta.y] * wa.y;
        va.z = r[ta.z] * wa.z; va.w = r[ta.w] * wa.w;
        vb.x = r[tb.x] * wb.x; vb.y = r[tb.y] * wb.y;
        vb.z = r[tb.z] * wb.z; vb.w = r[tb.w] * wb.w;

        // streaming stores: 256 MB never re-read — keep out of L2
        __builtin_nontemporal_store(va, (v4f*)(pixb + (size_t)s * NP + p));
        __builtin_nontemporal_store(vb, (v4f*)(pixb + (size_t)s * NP + p + 1024));
        acc0 += va; acc1 += vb;
    }

    // relu + das store
    acc0.x = fmaxf(acc0.x, 0.f); acc0.y = fmaxf(acc0.y, 0.f);
    acc0.z = fmaxf(acc0.z, 0.f); acc0.w = fmaxf(acc0.w, 0.f);
    acc1.x = fmaxf(acc1.x, 0.f); acc1.y = fmaxf(acc1.y, 0.f);
    acc1.z = fmaxf(acc1.z, 0.f); acc1.w = fmaxf(acc1.w, 0.f);
    *(v4f*)(das + (size_t)b * NP + p)        = acc0;
    *(v4f*)(das + (size_t)b * NP + p + 1024) = acc1;

    // block max -> per-batch atomic max
    float m = fmaxf(fmaxf(fmaxf(acc0.x, acc0.y), fmaxf(acc0.z, acc0.w)),
                    fmaxf(fmaxf(acc1.x, acc1.y), fmaxf(acc1.z, acc1.w)));
    #pragma unroll
    for (int off = 32; off > 0; off >>= 1)
        m = fmaxf(m, __shfl_down(m, off, 64));
    __shared__ float wm[4];
    if ((tid & 63) == 0) wm[tid >> 6] = m;
    __syncthreads();
    if (tid == 0) {
        m = fmaxf(fmaxf(wm[0], wm[1]), fmaxf(wm[2], wm[3]));
        atomicMax(&bmax[b], __float_as_uint(m));   // values >= 0: uint order == float order
    }
}

// ---------------------------------------------------------------------------
// Fallback main (no workspace): reads original geometry layout directly.
// ---------------------------------------------------------------------------
__global__ __launch_bounds__(256) void main_fallback_kernel(
    const float* __restrict__ sino,
    const int*   __restrict__ tptr,
    const float* __restrict__ wptr,
    float*       __restrict__ das,
    float*       __restrict__ pix,
    unsigned*    __restrict__ bmax)
{
    const int b = blockIdx.y;
    const int p = blockIdx.x * 1024 + threadIdx.x * 4;
    const float* __restrict__ srow = sino + (size_t)b * (NS * NT);
    float* __restrict__ pixb = pix + (size_t)b * ((size_t)NS * NP) + p;

    v4f acc = (v4f)(0.0f);
    for (int s = 0; s < NS; ++s) {
        int t0 = tptr[(p + 0) * NS + s];
        int t1 = tptr[(p + 1) * NS + s];
        int t2 = tptr[(p + 2) * NS + s];
        int t3 = tptr[(p + 3) * NS + s];
        float wx = ((t0 >= 0) & (t0 < NT)) ? wptr[(p + 0) * NS + s] : 0.f;
        float wy = ((t1 >= 0) & (t1 < NT)) ? wptr[(p + 1) * NS + s] : 0.f;
        float wz = ((t2 >= 0) & (t2 < NT)) ? wptr[(p + 2) * NS + s] : 0.f;
        float ww = ((t3 >= 0) & (t3 < NT)) ? wptr[(p + 3) * NS + s] : 0.f;
        const float* __restrict__ sr = srow + s * NT;
        v4f v;
        v.x = sr[min(max(t0, 0), NT - 1)] * wx;
        v.y = sr[min(max(t1, 0), NT - 1)] * wy;
        v.z = sr[min(max(t2, 0), NT - 1)] * wz;
        v.w = sr[min(max(t3, 0), NT - 1)] * ww;
        __builtin_nontemporal_store(v, (v4f*)(pixb + (size_t)s * NP));
        acc += v;
    }
    acc.x = fmaxf(acc.x, 0.f); acc.y = fmaxf(acc.y, 0.f);
    acc.z = fmaxf(acc.z, 0.f); acc.w = fmaxf(acc.w, 0.f);
    *(v4f*)(das + (size_t)b * NP + p) = acc;

    float m = fmaxf(fmaxf(acc.x, acc.y), fmaxf(acc.z, acc.w));
    #pragma unroll
    for (int off = 32; off > 0; off >>= 1)
        m = fmaxf(m, __shfl_down(m, off, 64));
    __shared__ float wm[4];
    if ((threadIdx.x & 63) == 0) wm[threadIdx.x >> 6] = m;
    __syncthreads();
    if (threadIdx.x == 0) {
        m = fmaxf(fmaxf(wm[0], wm[1]), fmaxf(wm[2], wm[3]));
        atomicMax(&bmax[b], __float_as_uint(m));
    }
}

// ---------------------------------------------------------------------------
// Kernel 2: normalize das in place.
// ---------------------------------------------------------------------------
__global__ __launch_bounds__(256) void norm_kernel(
    float* __restrict__ das, const unsigned* __restrict__ bmax)
{
    int idx = (blockIdx.x * 256 + threadIdx.x) * 4;
    int b = idx >> 14;                   // NP = 16384 pixels per batch
    float m = __uint_as_float(bmax[b]);
    m = (m > 1e-8f) ? m : 1.0f;
    v4f v = *(v4f*)(das + idx);
    v.x = v.x / m; v.y = v.y / m; v.z = v.z / m; v.w = v.w / m;
    *(v4f*)(das + idx) = v;
}

extern "C" void kernel_launch(void* const* d_in, const int* in_sizes, int n_in,
                              void* d_out, int out_size, void* d_ws, size_t ws_size,
                              hipStream_t stream)
{
    const float* sino  = (const float*)d_in[0];   // (64,1,64,2030) f32
    const float* w     = (const float*)d_in[1];   // (128,128,64)   f32
    const int*   t_idx = (const int*)  d_in[2];   // (128,128,64)   i32
    // d_in[3] (valid_mask) unused: valid == (0 <= t_idx < NT)

    float* das = (float*)d_out;                   // first 1,048,576 floats
    float* pix = (float*)d_out + DAS_ELEMS;       // next 67,108,864 floats

    char* ws = (char*)d_ws;
    const size_t need = (size_t)(8u << 20) + 256;
    const bool big = ws_size >= need;

    unsigned* bmax;
    int* tc = nullptr; float* wv = nullptr;
    if (big) {
        tc   = (int*)ws;                          // 4 MB
        wv   = (float*)(ws + (4u << 20));         // 4 MB
        bmax = (unsigned*)(ws + (8u << 20));      // 256 B
    } else {
        bmax = (unsigned*)ws;
    }

    (void)hipMemsetAsync(bmax, 0, NB * sizeof(unsigned), stream);

    if (big) {
        prep_kernel<<<256, 256, 0, stream>>>(t_idx, w, tc, wv);
        main2_kernel<<<dim3(8, NB), 256, 0, stream>>>(sino, tc, wv, das, pix, bmax);
    } else {
        main_fallback_kernel<<<dim3(16, NB), 256, 0, stream>>>(sino, t_idx, w, das, pix, bmax);
    }
    norm_kernel<<<DAS_ELEMS / 1024, 256, 0, stream>>>(das, bmax);
}